// Round 1
// baseline (439.071 us; speedup 1.0000x reference)
//
#include <hip/hip_runtime.h>
#include <hip/hip_bf16.h>

// ---------------------------------------------------------------------------
// GAT link predictor: 2x GATConv + pair MLP, fp32 end-to-end.
// N=50000, E=800000 (+N self loops), F_in=128, L1: 4 heads x 32, L2: 1 x 64,
// MLP: 128->32->1 over P=200000 pairs.
// ---------------------------------------------------------------------------

#define LRELU_SLOPE 0.2f

// ---- weight pre-transpose (so GEMM W reads are wave-uniform -> s_load) ----
__global__ void __launch_bounds__(256) prep_kernel(
    const float* __restrict__ W1, const float* __restrict__ W2,
    const float* __restrict__ Wm1,
    float* __restrict__ W1T, float* __restrict__ W2T, float* __restrict__ Wm1T)
{
    int i = blockIdx.x * 256 + threadIdx.x;
    if (i < 16384) {                       // W1 [128][128] -> W1T [128][128]
        int k = i >> 7, j = i & 127;
        W1T[j * 128 + k] = W1[i];
    } else if (i < 16384 + 8192) {         // W2 [128][64] -> W2T [64][128]
        int t = i - 16384;
        int k = t >> 6, j = t & 63;
        W2T[j * 128 + k] = W2[t];
    } else if (i < 16384 + 8192 + 4096) {  // Wm1 [128][32] -> Wm1T [32][128]
        int t = i - 24576;
        int k = t >> 5, j = t & 31;
        Wm1T[j * 128 + k] = Wm1[t];
    }
}

// ---- CSR build ----
__global__ void __launch_bounds__(256) hist_kernel(
    const int* __restrict__ dst, int E, int N, int* __restrict__ deg)
{
    int i = blockIdx.x * 256 + threadIdx.x;
    if (i >= E + N) return;
    int d = (i < E) ? dst[i] : (i - E);
    atomicAdd(deg + d, 1);
}

__global__ void __launch_bounds__(1024) scan_kernel(
    const int* __restrict__ deg, int* __restrict__ rowptr, int n)
{
    __shared__ int wsum[16];
    __shared__ int carryS;
    int t = threadIdx.x, lane = t & 63, wid = t >> 6;
    if (t == 0) carryS = 0;
    __syncthreads();
    for (int base = 0; base < n; base += 1024) {
        int idx = base + t;
        int v = (idx < n) ? deg[idx] : 0;
        // inclusive wave scan
        #pragma unroll
        for (int off = 1; off < 64; off <<= 1) {
            int y = __shfl_up(v, off);
            if (lane >= off) v += y;
        }
        if (lane == 63) wsum[wid] = v;
        __syncthreads();
        if (wid == 0) {
            int s = (lane < 16) ? wsum[lane] : 0;
            #pragma unroll
            for (int off = 1; off < 16; off <<= 1) {
                int y = __shfl_up(s, off);
                if (lane >= off) s += y;
            }
            if (lane < 16) wsum[lane] = s;
        }
        __syncthreads();
        int woff = (wid > 0) ? wsum[wid - 1] : 0;
        int c = carryS;
        int inc = c + woff + v;
        if (idx < n) rowptr[idx + 1] = inc;
        if (idx == 0) rowptr[0] = 0;
        __syncthreads();
        if (t == 1023) carryS = inc;
        __syncthreads();
    }
}

__global__ void __launch_bounds__(256) scatter_kernel(
    const int* __restrict__ src, const int* __restrict__ dst, int E, int N,
    const int* __restrict__ rowptr, int* __restrict__ cursor,
    int* __restrict__ csrs)
{
    int i = blockIdx.x * 256 + threadIdx.x;
    if (i >= E + N) return;
    int s, d;
    if (i < E) { s = src[i]; d = dst[i]; } else { s = d = i - E; }
    int pos = rowptr[d] + atomicAdd(cursor + d, 1);
    csrs[pos] = s;
}

// ---- fused GEMM + attention-score epilogue ----
// Block: 256 threads = 4 waves. Block computes 64 rows x 64 cols.
// lane = row (x in LDS, stride 132 => conflict-free b128 along k),
// wave = 16-col slice, W reads wave-uniform -> scalar loads.
__global__ void __launch_bounds__(256) gemm_att_kernel(
    const float* __restrict__ X, const float* __restrict__ WT,
    const float* __restrict__ atts, const float* __restrict__ attd,
    float* __restrict__ OUT, float* __restrict__ oas, float* __restrict__ oad,
    int N, int ncols, int H, int headShift)
{
    __shared__ float xs[64 * 132];
    int tid = threadIdx.x;
    int rowBase = blockIdx.x * 64;
    int colBase = blockIdx.y * 64;
    for (int i = tid; i < 64 * 32; i += 256) {
        int r = i >> 5, k4 = i & 31;
        int gr = rowBase + r;
        float4 v = (gr < N) ? ((const float4*)(X + (size_t)gr * 128))[k4]
                            : make_float4(0.f, 0.f, 0.f, 0.f);
        *(float4*)(xs + r * 132 + k4 * 4) = v;
    }
    __syncthreads();
    int lane = tid & 63;
    int wv = __builtin_amdgcn_readfirstlane(tid >> 6);
    int jb = colBase + wv * 16;
    const float* wbase = WT + (size_t)jb * 128;
    float acc[16];
    #pragma unroll
    for (int i = 0; i < 16; i++) acc[i] = 0.f;
    const float* xr = xs + lane * 132;
    for (int k0 = 0; k0 < 128; k0 += 4) {
        float4 xv = *(const float4*)(xr + k0);
        #pragma unroll
        for (int i = 0; i < 16; i++) {
            const float* wr = wbase + i * 128 + k0;   // uniform -> s_load
            acc[i] = fmaf(xv.x, wr[0], acc[i]);
            acc[i] = fmaf(xv.y, wr[1], acc[i]);
            acc[i] = fmaf(xv.z, wr[2], acc[i]);
            acc[i] = fmaf(xv.w, wr[3], acc[i]);
        }
    }
    int row = rowBase + lane;
    if (row < N) {
        float pas = 0.f, pad_ = 0.f;
        #pragma unroll
        for (int i = 0; i < 16; i++) {
            pas  = fmaf(acc[i], atts[jb + i], pas);
            pad_ = fmaf(acc[i], attd[jb + i], pad_);
        }
        int head = jb >> headShift;
        atomicAdd(oas + (size_t)row * H + head, pas);
        atomicAdd(oad + (size_t)row * H + head, pad_);
        float* op = OUT + (size_t)row * ncols + jb;
        #pragma unroll
        for (int i = 0; i < 16; i += 4)
            *(float4*)(op + i) = make_float4(acc[i], acc[i+1], acc[i+2], acc[i+3]);
    }
}

// ---- layer-1 edge pass: softmax (no max-sub; invariant) + weighted gather ----
// One wave per node. lane covers channels {2*lane, 2*lane+1}; head = lane>>4.
// Phase 1 per 16-edge chunk: lane = (edge<<2)|head computes w=exp(lrelu(...)).
__global__ void __launch_bounds__(256) edgepass1_kernel(
    const int* __restrict__ csrs, const int* __restrict__ rowptr,
    const float* __restrict__ h1, const float* __restrict__ as1,
    const float* __restrict__ ad1, const float* __restrict__ b1,
    float* __restrict__ x2, int N)
{
    int lane = threadIdx.x & 63;
    int n = __builtin_amdgcn_readfirstlane(blockIdx.x * 4 + (threadIdx.x >> 6));
    if (n >= N) return;
    int rs = rowptr[n], re = rowptr[n + 1];
    int hd = lane >> 4;                 // head of my two channels
    float adv = ad1[n * 4 + (lane & 3)];  // alpha_dst for phase-1 role
    float accx = 0.f, accy = 0.f;
    float srun = 0.f;                   // running denom for head (lane&3)
    for (int base = rs; base < re; base += 16) {
        int cnt = re - base; if (cnt > 16) cnt = 16;
        int el = lane >> 2, hh = lane & 3;
        float wv = 0.f; int s = 0;
        if (el < cnt) {
            s = csrs[base + el];
            float e = as1[(size_t)s * 4 + hh] + adv;
            e = e > 0.f ? e : LRELU_SLOPE * e;
            wv = __expf(e);
        }
        float t = wv;
        t += __shfl_xor(t, 4); t += __shfl_xor(t, 8);
        t += __shfl_xor(t, 16); t += __shfl_xor(t, 32);
        srun += t;
        #pragma unroll 2
        for (int e2 = 0; e2 < cnt; ++e2) {
            int sn  = __shfl(s, e2 << 2);
            float av = __shfl(wv, (e2 << 2) | hd);
            float2 v = *(const float2*)(h1 + (size_t)sn * 128 + lane * 2);
            accx = fmaf(av, v.x, accx);
            accy = fmaf(av, v.y, accy);
        }
    }
    float sden = __shfl(srun, hd) + 1e-16f;
    float inv = 1.f / sden;
    float2 bv = *(const float2*)(b1 + lane * 2);
    float o0 = accx * inv + bv.x;
    float o1 = accy * inv + bv.y;
    o0 = o0 > 0.f ? o0 : (__expf(o0) - 1.f);   // ELU
    o1 = o1 > 0.f ? o1 : (__expf(o1) - 1.f);
    *(float2*)(x2 + (size_t)n * 128 + lane * 2) = make_float2(o0, o1);
}

// ---- layer-2 edge pass (1 head, 64 channels) ----
__global__ void __launch_bounds__(256) edgepass2_kernel(
    const int* __restrict__ csrs, const int* __restrict__ rowptr,
    const float* __restrict__ h2, const float* __restrict__ as2,
    const float* __restrict__ ad2, const float* __restrict__ b2,
    float* __restrict__ hf, int N)
{
    int lane = threadIdx.x & 63;
    int n = __builtin_amdgcn_readfirstlane(blockIdx.x * 4 + (threadIdx.x >> 6));
    if (n >= N) return;
    int rs = rowptr[n], re = rowptr[n + 1];
    float adv = ad2[n];
    float acc = 0.f, srun = 0.f;
    for (int base = rs; base < re; base += 64) {
        int cnt = re - base; if (cnt > 64) cnt = 64;
        float wv = 0.f; int s = 0;
        if (lane < cnt) {
            s = csrs[base + lane];
            float e = as2[s] + adv;
            e = e > 0.f ? e : LRELU_SLOPE * e;
            wv = __expf(e);
        }
        srun += wv;
        #pragma unroll 2
        for (int e2 = 0; e2 < cnt; ++e2) {
            int sn  = __shfl(s, e2);
            float av = __shfl(wv, e2);
            acc = fmaf(av, h2[(size_t)sn * 64 + lane], acc);
        }
    }
    #pragma unroll
    for (int m = 1; m < 64; m <<= 1) srun += __shfl_xor(srun, m);
    float o = acc / (srun + 1e-16f) + b2[lane];
    hf[(size_t)n * 64 + lane] = o;
}

// ---- pair MLP: lane = pair; W uniform -> scalar loads ----
__global__ void __launch_bounds__(256) mlp_kernel(
    const int* __restrict__ ps, const int* __restrict__ pd,
    const float* __restrict__ hf, const float* __restrict__ Wm1T,
    const float* __restrict__ bm1, const float* __restrict__ Wm2,
    const float* __restrict__ bm2, float* __restrict__ out, int P)
{
    int p = blockIdx.x * 256 + threadIdx.x;
    if (p >= P) return;
    int a = ps[p], b = pd[p];
    const float* ha = hf + (size_t)a * 64;
    const float* hb = hf + (size_t)b * 64;
    float hid[32];
    #pragma unroll
    for (int j = 0; j < 32; j++) hid[j] = 0.f;
    #pragma unroll 1
    for (int c = 0; c < 4; c++) {
        const float* src = (c < 2 ? ha : hb) + (c & 1) * 32;
        float ev[32];
        #pragma unroll
        for (int q = 0; q < 8; q++) {
            float4 t = ((const float4*)src)[q];
            ev[q*4] = t.x; ev[q*4+1] = t.y; ev[q*4+2] = t.z; ev[q*4+3] = t.w;
        }
        #pragma unroll
        for (int j = 0; j < 32; j++) {
            const float* wr = Wm1T + j * 128 + c * 32;  // uniform -> s_load
            #pragma unroll
            for (int k = 0; k < 32; k++)
                hid[j] = fmaf(ev[k], wr[k], hid[j]);
        }
    }
    float o = bm2[0];
    #pragma unroll
    for (int j = 0; j < 32; j++) {
        float hj = hid[j] + bm1[j];
        hj = hj > 0.f ? hj : 0.f;
        o = fmaf(hj, Wm2[j], o);
    }
    out[p] = o;
}

extern "C" void kernel_launch(void* const* d_in, const int* in_sizes, int n_in,
                              void* d_out, int out_size, void* d_ws, size_t ws_size,
                              hipStream_t stream)
{
    const float* x    = (const float*)d_in[0];
    const int*   ei   = (const int*)  d_in[1];
    const int*   ep   = (const int*)  d_in[2];
    const float* W1   = (const float*)d_in[3];
    const float* atS1 = (const float*)d_in[4];
    const float* atD1 = (const float*)d_in[5];
    const float* b1   = (const float*)d_in[6];
    const float* W2   = (const float*)d_in[7];
    const float* atS2 = (const float*)d_in[8];
    const float* atD2 = (const float*)d_in[9];
    const float* b2   = (const float*)d_in[10];
    const float* Wm1  = (const float*)d_in[11];
    const float* bm1  = (const float*)d_in[12];
    const float* Wm2  = (const float*)d_in[13];
    const float* bm2  = (const float*)d_in[14];
    float* out = (float*)d_out;

    int N = in_sizes[0] / 128;
    int E = in_sizes[1] / 2;
    int P = in_sizes[2] / 2;

    // workspace carve (256B aligned)
    char* w = (char*)d_ws;
    auto alloc = [&](size_t bytes) {
        char* p = w; w += (bytes + 255) & ~(size_t)255; return p;
    };
    float* W1T  = (float*)alloc(16384 * 4);
    float* W2T  = (float*)alloc(8192 * 4);
    float* Wm1T = (float*)alloc(4096 * 4);
    float* h1   = (float*)alloc((size_t)N * 128 * 4);
    float* x2   = (float*)alloc((size_t)N * 128 * 4);
    float* h2   = (float*)alloc((size_t)N * 64 * 4);
    float* hf   = (float*)alloc((size_t)N * 64 * 4);
    float* as1  = (float*)alloc((size_t)N * 4 * 4);
    float* ad1  = (float*)alloc((size_t)N * 4 * 4);
    float* as2  = (float*)alloc((size_t)N * 4);
    float* ad2  = (float*)alloc((size_t)N * 4);
    int*   deg  = (int*)alloc((size_t)N * 4);
    int*   rowp = (int*)alloc((size_t)(N + 1) * 4);
    int*   curs = (int*)alloc((size_t)N * 4);
    int*   csrs = (int*)alloc((size_t)(E + N) * 4);

    (void)hipMemsetAsync(deg,  0, (size_t)N * 4, stream);
    (void)hipMemsetAsync(curs, 0, (size_t)N * 4, stream);
    (void)hipMemsetAsync(as1,  0, (size_t)N * 16, stream);
    (void)hipMemsetAsync(ad1,  0, (size_t)N * 16, stream);
    (void)hipMemsetAsync(as2,  0, (size_t)N * 4, stream);
    (void)hipMemsetAsync(ad2,  0, (size_t)N * 4, stream);

    prep_kernel<<<112, 256, 0, stream>>>(W1, W2, Wm1, W1T, W2T, Wm1T);

    int EN = E + N;
    hist_kernel<<<(EN + 255) / 256, 256, 0, stream>>>(ei + E, E, N, deg);
    scan_kernel<<<1, 1024, 0, stream>>>(deg, rowp, N);
    scatter_kernel<<<(EN + 255) / 256, 256, 0, stream>>>(ei, ei + E, E, N, rowp, curs, csrs);

    dim3 g1((N + 63) / 64, 2);
    gemm_att_kernel<<<g1, 256, 0, stream>>>(x, W1T, atS1, atD1, h1, as1, ad1,
                                            N, 128, 4, 5);
    edgepass1_kernel<<<(N + 3) / 4, 256, 0, stream>>>(csrs, rowp, h1, as1, ad1,
                                                      b1, x2, N);
    dim3 g2((N + 63) / 64, 1);
    gemm_att_kernel<<<g2, 256, 0, stream>>>(x2, W2T, atS2, atD2, h2, as2, ad2,
                                            N, 64, 1, 6);
    edgepass2_kernel<<<(N + 3) / 4, 256, 0, stream>>>(csrs, rowp, h2, as2, ad2,
                                                      b2, hf, N);
    mlp_kernel<<<(P + 255) / 256, 256, 0, stream>>>(ep, ep + P, hf, Wm1T, bm1,
                                                    Wm2, bm2, out, P);
}

// Round 2
// 395.762 us; speedup vs baseline: 1.1094x; 1.1094x over previous
//
#include <hip/hip_runtime.h>
#include <hip/hip_bf16.h>

// ---------------------------------------------------------------------------
// GAT link predictor: 2x GATConv + pair MLP, fp32 end-to-end.
// N=50000, E=800000 (+N self loops), F_in=128, L1: 4 heads x 32, L2: 1 x 64,
// MLP: 128->32->1 over P=200000 pairs.
// R2: factorized pair MLP -> per-node u/v projections + tiny pair kernel
//     (2 lanes per pair for occupancy).
// ---------------------------------------------------------------------------

#define LRELU_SLOPE 0.2f

// ---- weight pre-transpose (so GEMM W reads are wave-uniform -> s_load) ----
__global__ void __launch_bounds__(256) prep_kernel(
    const float* __restrict__ W1, const float* __restrict__ W2,
    const float* __restrict__ Wm1,
    float* __restrict__ W1T, float* __restrict__ W2T, float* __restrict__ Wm1T)
{
    int i = blockIdx.x * 256 + threadIdx.x;
    if (i < 16384) {                       // W1 [128][128] -> W1T [128][128]
        int k = i >> 7, j = i & 127;
        W1T[j * 128 + k] = W1[i];
    } else if (i < 16384 + 8192) {         // W2 [128][64] -> W2T [64][128]
        int t = i - 16384;
        int k = t >> 6, j = t & 63;
        W2T[j * 128 + k] = W2[t];
    } else if (i < 16384 + 8192 + 4096) {  // Wm1 [128][32] -> Wm1T [32][128]
        int t = i - 24576;
        int k = t >> 5, j = t & 31;
        Wm1T[j * 128 + k] = Wm1[t];
    }
}

// ---- CSR build ----
__global__ void __launch_bounds__(256) hist_kernel(
    const int* __restrict__ dst, int E, int N, int* __restrict__ deg)
{
    int i = blockIdx.x * 256 + threadIdx.x;
    if (i >= E + N) return;
    int d = (i < E) ? dst[i] : (i - E);
    atomicAdd(deg + d, 1);
}

__global__ void __launch_bounds__(1024) scan_kernel(
    const int* __restrict__ deg, int* __restrict__ rowptr, int n)
{
    __shared__ int wsum[16];
    __shared__ int carryS;
    int t = threadIdx.x, lane = t & 63, wid = t >> 6;
    if (t == 0) carryS = 0;
    __syncthreads();
    for (int base = 0; base < n; base += 1024) {
        int idx = base + t;
        int v = (idx < n) ? deg[idx] : 0;
        // inclusive wave scan
        #pragma unroll
        for (int off = 1; off < 64; off <<= 1) {
            int y = __shfl_up(v, off);
            if (lane >= off) v += y;
        }
        if (lane == 63) wsum[wid] = v;
        __syncthreads();
        if (wid == 0) {
            int s = (lane < 16) ? wsum[lane] : 0;
            #pragma unroll
            for (int off = 1; off < 16; off <<= 1) {
                int y = __shfl_up(s, off);
                if (lane >= off) s += y;
            }
            if (lane < 16) wsum[lane] = s;
        }
        __syncthreads();
        int woff = (wid > 0) ? wsum[wid - 1] : 0;
        int c = carryS;
        int inc = c + woff + v;
        if (idx < n) rowptr[idx + 1] = inc;
        if (idx == 0) rowptr[0] = 0;
        __syncthreads();
        if (t == 1023) carryS = inc;
        __syncthreads();
    }
}

__global__ void __launch_bounds__(256) scatter_kernel(
    const int* __restrict__ src, const int* __restrict__ dst, int E, int N,
    const int* __restrict__ rowptr, int* __restrict__ cursor,
    int* __restrict__ csrs)
{
    int i = blockIdx.x * 256 + threadIdx.x;
    if (i >= E + N) return;
    int s, d;
    if (i < E) { s = src[i]; d = dst[i]; } else { s = d = i - E; }
    int pos = rowptr[d] + atomicAdd(cursor + d, 1);
    csrs[pos] = s;
}

// ---- fused GEMM + attention-score epilogue ----
// Block: 256 threads = 4 waves. Block computes 64 rows x 64 cols.
// lane = row (x in LDS, stride 132 => conflict-free b128 along k),
// wave = 16-col slice, W reads wave-uniform -> scalar loads.
__global__ void __launch_bounds__(256) gemm_att_kernel(
    const float* __restrict__ X, const float* __restrict__ WT,
    const float* __restrict__ atts, const float* __restrict__ attd,
    float* __restrict__ OUT, float* __restrict__ oas, float* __restrict__ oad,
    int N, int ncols, int H, int headShift)
{
    __shared__ float xs[64 * 132];
    int tid = threadIdx.x;
    int rowBase = blockIdx.x * 64;
    int colBase = blockIdx.y * 64;
    for (int i = tid; i < 64 * 32; i += 256) {
        int r = i >> 5, k4 = i & 31;
        int gr = rowBase + r;
        float4 v = (gr < N) ? ((const float4*)(X + (size_t)gr * 128))[k4]
                            : make_float4(0.f, 0.f, 0.f, 0.f);
        *(float4*)(xs + r * 132 + k4 * 4) = v;
    }
    __syncthreads();
    int lane = tid & 63;
    int wv = __builtin_amdgcn_readfirstlane(tid >> 6);
    int jb = colBase + wv * 16;
    const float* wbase = WT + (size_t)jb * 128;
    float acc[16];
    #pragma unroll
    for (int i = 0; i < 16; i++) acc[i] = 0.f;
    const float* xr = xs + lane * 132;
    for (int k0 = 0; k0 < 128; k0 += 4) {
        float4 xv = *(const float4*)(xr + k0);
        #pragma unroll
        for (int i = 0; i < 16; i++) {
            const float* wr = wbase + i * 128 + k0;   // uniform -> s_load
            acc[i] = fmaf(xv.x, wr[0], acc[i]);
            acc[i] = fmaf(xv.y, wr[1], acc[i]);
            acc[i] = fmaf(xv.z, wr[2], acc[i]);
            acc[i] = fmaf(xv.w, wr[3], acc[i]);
        }
    }
    int row = rowBase + lane;
    if (row < N) {
        float pas = 0.f, pad_ = 0.f;
        #pragma unroll
        for (int i = 0; i < 16; i++) {
            pas  = fmaf(acc[i], atts[jb + i], pas);
            pad_ = fmaf(acc[i], attd[jb + i], pad_);
        }
        int head = jb >> headShift;
        atomicAdd(oas + (size_t)row * H + head, pas);
        atomicAdd(oad + (size_t)row * H + head, pad_);
        float* op = OUT + (size_t)row * ncols + jb;
        #pragma unroll
        for (int i = 0; i < 16; i += 4)
            *(float4*)(op + i) = make_float4(acc[i], acc[i+1], acc[i+2], acc[i+3]);
    }
}

// ---- layer-1 edge pass: softmax (no max-sub; invariant) + weighted gather ----
// One wave per node. lane covers channels {2*lane, 2*lane+1}; head = lane>>4.
// Phase 1 per 16-edge chunk: lane = (edge<<2)|head computes w=exp(lrelu(...)).
__global__ void __launch_bounds__(256) edgepass1_kernel(
    const int* __restrict__ csrs, const int* __restrict__ rowptr,
    const float* __restrict__ h1, const float* __restrict__ as1,
    const float* __restrict__ ad1, const float* __restrict__ b1,
    float* __restrict__ x2, int N)
{
    int lane = threadIdx.x & 63;
    int n = __builtin_amdgcn_readfirstlane(blockIdx.x * 4 + (threadIdx.x >> 6));
    if (n >= N) return;
    int rs = rowptr[n], re = rowptr[n + 1];
    int hd = lane >> 4;                 // head of my two channels
    float adv = ad1[n * 4 + (lane & 3)];  // alpha_dst for phase-1 role
    float accx = 0.f, accy = 0.f;
    float srun = 0.f;                   // running denom for head (lane&3)
    for (int base = rs; base < re; base += 16) {
        int cnt = re - base; if (cnt > 16) cnt = 16;
        int el = lane >> 2, hh = lane & 3;
        float wv = 0.f; int s = 0;
        if (el < cnt) {
            s = csrs[base + el];
            float e = as1[(size_t)s * 4 + hh] + adv;
            e = e > 0.f ? e : LRELU_SLOPE * e;
            wv = __expf(e);
        }
        float t = wv;
        t += __shfl_xor(t, 4); t += __shfl_xor(t, 8);
        t += __shfl_xor(t, 16); t += __shfl_xor(t, 32);
        srun += t;
        #pragma unroll 2
        for (int e2 = 0; e2 < cnt; ++e2) {
            int sn  = __shfl(s, e2 << 2);
            float av = __shfl(wv, (e2 << 2) | hd);
            float2 v = *(const float2*)(h1 + (size_t)sn * 128 + lane * 2);
            accx = fmaf(av, v.x, accx);
            accy = fmaf(av, v.y, accy);
        }
    }
    float sden = __shfl(srun, hd) + 1e-16f;
    float inv = 1.f / sden;
    float2 bv = *(const float2*)(b1 + lane * 2);
    float o0 = accx * inv + bv.x;
    float o1 = accy * inv + bv.y;
    o0 = o0 > 0.f ? o0 : (__expf(o0) - 1.f);   // ELU
    o1 = o1 > 0.f ? o1 : (__expf(o1) - 1.f);
    *(float2*)(x2 + (size_t)n * 128 + lane * 2) = make_float2(o0, o1);
}

// ---- layer-2 edge pass (1 head, 64 channels) ----
__global__ void __launch_bounds__(256) edgepass2_kernel(
    const int* __restrict__ csrs, const int* __restrict__ rowptr,
    const float* __restrict__ h2, const float* __restrict__ as2,
    const float* __restrict__ ad2, const float* __restrict__ b2,
    float* __restrict__ hf, int N)
{
    int lane = threadIdx.x & 63;
    int n = __builtin_amdgcn_readfirstlane(blockIdx.x * 4 + (threadIdx.x >> 6));
    if (n >= N) return;
    int rs = rowptr[n], re = rowptr[n + 1];
    float adv = ad2[n];
    float acc = 0.f, srun = 0.f;
    for (int base = rs; base < re; base += 64) {
        int cnt = re - base; if (cnt > 64) cnt = 64;
        float wv = 0.f; int s = 0;
        if (lane < cnt) {
            s = csrs[base + lane];
            float e = as2[s] + adv;
            e = e > 0.f ? e : LRELU_SLOPE * e;
            wv = __expf(e);
        }
        srun += wv;
        #pragma unroll 2
        for (int e2 = 0; e2 < cnt; ++e2) {
            int sn  = __shfl(s, e2);
            float av = __shfl(wv, e2);
            acc = fmaf(av, h2[(size_t)sn * 64 + lane], acc);
        }
    }
    #pragma unroll
    for (int m = 1; m < 64; m <<= 1) srun += __shfl_xor(srun, m);
    float o = acc / (srun + 1e-16f) + b2[lane];
    hf[(size_t)n * 64 + lane] = o;
}

// ---- per-node MLP projections: u[n] = hf[n]@Wm1_top, v[n] = hf[n]@Wm1_bot --
// wave per node (grid-stride). lane: half = lane>>5 (0=u, 1=v), j = lane&31.
// Weights hoisted to registers once per wave; hf row reads are wave-uniform.
__global__ void __launch_bounds__(256) node_mlp_kernel(
    const float* __restrict__ hf, const float* __restrict__ Wm1T,
    float* __restrict__ uv, int N)
{
    int lane = threadIdx.x & 63;
    int j = lane & 31, half = lane >> 5;
    const float* wr = Wm1T + j * 128 + half * 64;   // Wm1T[j][half*64 + k]
    float wreg[64];
    #pragma unroll
    for (int q = 0; q < 16; q++) {
        float4 t = ((const float4*)wr)[q];
        wreg[q*4] = t.x; wreg[q*4+1] = t.y; wreg[q*4+2] = t.z; wreg[q*4+3] = t.w;
    }
    int wgid = __builtin_amdgcn_readfirstlane(blockIdx.x * 4 + (threadIdx.x >> 6));
    int nwaves = gridDim.x * 4;
    for (int n = wgid; n < N; n += nwaves) {
        const float* hr = hf + (size_t)n * 64;
        float acc = 0.f;
        #pragma unroll
        for (int k = 0; k < 64; k += 4) {
            float4 hv = *(const float4*)(hr + k);   // uniform across wave
            acc = fmaf(hv.x, wreg[k],   acc);
            acc = fmaf(hv.y, wreg[k+1], acc);
            acc = fmaf(hv.z, wreg[k+2], acc);
            acc = fmaf(hv.w, wreg[k+3], acc);
        }
        uv[(size_t)n * 64 + lane] = acc;
    }
}

// ---- pair MLP: 2 lanes per pair (16 hidden units each), shfl-reduce ----
__global__ void __launch_bounds__(256) pair_mlp_kernel(
    const int* __restrict__ ps, const int* __restrict__ pd,
    const float* __restrict__ uv, const float* __restrict__ bm1,
    const float* __restrict__ Wm2, const float* __restrict__ bm2,
    float* __restrict__ out, int P)
{
    int gid = blockIdx.x * 256 + threadIdx.x;
    int p = gid >> 1;
    if (p >= P) return;
    int half = gid & 1;
    int j0 = half * 16;
    int a = ps[p], b = pd[p];
    const float* ua = uv + (size_t)a * 64 + j0;        // u[a][j0:j0+16]
    const float* vb = uv + (size_t)b * 64 + 32 + j0;   // v[b][j0:j0+16]
    float r = 0.f;
    #pragma unroll
    for (int q = 0; q < 4; q++) {
        float4 uu = ((const float4*)ua)[q];
        float4 vv = ((const float4*)vb)[q];
        float4 bb = ((const float4*)(bm1 + j0))[q];
        float4 ww = ((const float4*)(Wm2 + j0))[q];
        float h0 = uu.x + vv.x + bb.x; h0 = h0 > 0.f ? h0 : 0.f; r = fmaf(h0, ww.x, r);
        float h1 = uu.y + vv.y + bb.y; h1 = h1 > 0.f ? h1 : 0.f; r = fmaf(h1, ww.y, r);
        float h2 = uu.z + vv.z + bb.z; h2 = h2 > 0.f ? h2 : 0.f; r = fmaf(h2, ww.z, r);
        float h3 = uu.w + vv.w + bb.w; h3 = h3 > 0.f ? h3 : 0.f; r = fmaf(h3, ww.w, r);
    }
    r += __shfl_xor(r, 1);
    if (half == 0) out[p] = r + bm2[0];
}

extern "C" void kernel_launch(void* const* d_in, const int* in_sizes, int n_in,
                              void* d_out, int out_size, void* d_ws, size_t ws_size,
                              hipStream_t stream)
{
    const float* x    = (const float*)d_in[0];
    const int*   ei   = (const int*)  d_in[1];
    const int*   ep   = (const int*)  d_in[2];
    const float* W1   = (const float*)d_in[3];
    const float* atS1 = (const float*)d_in[4];
    const float* atD1 = (const float*)d_in[5];
    const float* b1   = (const float*)d_in[6];
    const float* W2   = (const float*)d_in[7];
    const float* atS2 = (const float*)d_in[8];
    const float* atD2 = (const float*)d_in[9];
    const float* b2   = (const float*)d_in[10];
    const float* Wm1  = (const float*)d_in[11];
    const float* bm1  = (const float*)d_in[12];
    const float* Wm2  = (const float*)d_in[13];
    const float* bm2  = (const float*)d_in[14];
    float* out = (float*)d_out;

    int N = in_sizes[0] / 128;
    int E = in_sizes[1] / 2;
    int P = in_sizes[2] / 2;

    // workspace carve (256B aligned)
    char* w = (char*)d_ws;
    auto alloc = [&](size_t bytes) {
        char* p = w; w += (bytes + 255) & ~(size_t)255; return p;
    };
    float* W1T  = (float*)alloc(16384 * 4);
    float* W2T  = (float*)alloc(8192 * 4);
    float* Wm1T = (float*)alloc(4096 * 4);
    float* h1   = (float*)alloc((size_t)N * 128 * 4);
    float* x2   = (float*)alloc((size_t)N * 128 * 4);
    float* h2   = (float*)alloc((size_t)N * 64 * 4);
    float* hf   = (float*)alloc((size_t)N * 64 * 4);
    float* as1  = (float*)alloc((size_t)N * 4 * 4);
    float* ad1  = (float*)alloc((size_t)N * 4 * 4);
    float* as2  = (float*)alloc((size_t)N * 4);
    float* ad2  = (float*)alloc((size_t)N * 4);
    int*   deg  = (int*)alloc((size_t)N * 4);
    int*   rowp = (int*)alloc((size_t)(N + 1) * 4);
    int*   curs = (int*)alloc((size_t)N * 4);
    int*   csrs = (int*)alloc((size_t)(E + N) * 4);
    float* uv   = h1;   // h1 is dead after edgepass1; reuse for u/v (N*64 fp32)

    (void)hipMemsetAsync(deg,  0, (size_t)N * 4, stream);
    (void)hipMemsetAsync(curs, 0, (size_t)N * 4, stream);
    (void)hipMemsetAsync(as1,  0, (size_t)N * 16, stream);
    (void)hipMemsetAsync(ad1,  0, (size_t)N * 16, stream);
    (void)hipMemsetAsync(as2,  0, (size_t)N * 4, stream);
    (void)hipMemsetAsync(ad2,  0, (size_t)N * 4, stream);

    prep_kernel<<<112, 256, 0, stream>>>(W1, W2, Wm1, W1T, W2T, Wm1T);

    int EN = E + N;
    hist_kernel<<<(EN + 255) / 256, 256, 0, stream>>>(ei + E, E, N, deg);
    scan_kernel<<<1, 1024, 0, stream>>>(deg, rowp, N);
    scatter_kernel<<<(EN + 255) / 256, 256, 0, stream>>>(ei, ei + E, E, N, rowp, curs, csrs);

    dim3 g1((N + 63) / 64, 2);
    gemm_att_kernel<<<g1, 256, 0, stream>>>(x, W1T, atS1, atD1, h1, as1, ad1,
                                            N, 128, 4, 5);
    edgepass1_kernel<<<(N + 3) / 4, 256, 0, stream>>>(csrs, rowp, h1, as1, ad1,
                                                      b1, x2, N);
    dim3 g2((N + 63) / 64, 1);
    gemm_att_kernel<<<g2, 256, 0, stream>>>(x2, W2T, atS2, atD2, h2, as2, ad2,
                                            N, 64, 1, 6);
    edgepass2_kernel<<<(N + 3) / 4, 256, 0, stream>>>(csrs, rowp, h2, as2, ad2,
                                                      b2, hf, N);

    node_mlp_kernel<<<1024, 256, 0, stream>>>(hf, Wm1T, uv, N);
    pair_mlp_kernel<<<(2 * P + 255) / 256, 256, 0, stream>>>(ep, ep + P, uv, bm1,
                                                             Wm2, bm2, out, P);
}